// Round 1
// baseline (39456.970 us; speedup 1.0000x reference)
//
#include <hip/hip_runtime.h>
#include <cstdint>
#include <cstddef>

// ---------------------------------------------------------------------------
// StepWiseMLPAutoEncoder  (MI355X / gfx950)  — round 1: fp32 correct baseline
//   enc sizes: 2049 -> 944 -> 416 -> 32   (relu, relu, linear), M = 16384
//   dec sizes: 1057 -> 1046 -> 1035 -> 1024, 256 sequential steps, B=64 rows
// Decoder = persistent cooperative kernel, LDS-resident weights, 3 global
// barriers/step, atomicAdd K-split partials, feature-major activations.
// ---------------------------------------------------------------------------

#define TT 256
#define BB 64
#define SS 1024
#define MROWS 16384

#define EK1 2049
#define EN1 944
#define EN2 416
#define EN3 32

#define DK1 1057
#define DN1 1046
#define DN2 1035
#define DN3 1024

// ws layout (float offsets). Total = 56,692,880 floats = ~216 MiB.
#define OFF_XT    ((size_t)0)
#define OFF_E1    ((size_t)16777216)                 // 16384*1024
#define OFF_E2    ((size_t)(OFF_E1 + 15466496))      // 16384*944
#define OFF_CTRL  ((size_t)(OFF_E2 + 6815744))       // 16384*416
#define OFF_RECON ((size_t)(OFF_CTRL + 524288))      // 256*32*64
#define OFF_H1    ((size_t)(OFF_RECON + 16842752))   // 257*1024*64
#define OFF_H2    ((size_t)(OFF_H1 + 133888))        // 2*1046*64
#define OFF_BAR   ((size_t)(OFF_H2 + 132480))        // 2*1035*64
#define ZERO_N    ((size_t)(16842752 + 133888 + 132480 + 16))

#define DEC_SMEM (343*68*4)   // 93,296 B dynamic LDS for decoder

// ---------------------------------------------------------------------------
__global__ void zero_init(float* __restrict__ p, size_t n) {
  size_t i = (size_t)blockIdx.x * blockDim.x + threadIdx.x;
  size_t stride = (size_t)gridDim.x * blockDim.x;
  for (; i < n; i += stride) p[i] = 0.f;
}

// x[b][s][t] -> xt[b][t][s]
__global__ void transpose_x(const float* __restrict__ x, float* __restrict__ xt) {
  __shared__ float tile[32][33];
  int b = blockIdx.z;
  int s0 = blockIdx.x << 5;   // S/32 = 32 tiles
  int t0 = blockIdx.y << 5;   // T/32 = 8 tiles
  int lt = threadIdx.x & 31;
  int ls = threadIdx.x >> 5;  // 0..7
  const float* xp = x + (size_t)b * SS * TT;
#pragma unroll
  for (int i = 0; i < 4; i++) {
    int s = s0 + ls + (i << 3);
    tile[ls + (i << 3)][lt] = xp[(size_t)s * TT + t0 + lt];
  }
  __syncthreads();
  float* xtp = xt + (size_t)b * TT * SS;
#pragma unroll
  for (int i = 0; i < 4; i++) {
    int t = t0 + ls + (i << 3);
    xtp[(size_t)t * SS + s0 + lt] = tile[lt][ls + (i << 3)];
  }
}

// virtual A for encoder layer 1: row m=(b,t), k: [prev(1024) | cur(1024) | t/T | pad]
__device__ inline float4 e1_fetch(const float* __restrict__ xt, int m, int kg) {
  float4 z; z.x = z.y = z.z = z.w = 0.f;
  int t = m & 255;
  if (kg < 1024) {
    if (t == 0) return z;
    return *(const float4*)(xt + (((size_t)(m - 1)) << 10) + kg);
  } else if (kg < 2048) {
    return *(const float4*)(xt + (((size_t)m) << 10) + (kg - 1024));
  } else if (kg == 2048) {
    z.x = (float)t * (1.0f / 256.0f);
    return z;
  }
  return z;
}

// ---------------------------------------------------------------------------
// Tiled fp32 GEMM: C[M][N] = act(A[M][K] @ B[K][N] + bias). BM=128 BN=64 BK=16.
// AMODE: 0 = plain row-major A, 1 = virtual encoder-L1 A (from xt).
// SCATTER: epilogue writes ctrl[t][f][b] (feature-major controls) instead of C.
template <int AMODE, bool RELU, bool SCATTER>
__global__ __launch_bounds__(256, 2) void gemm_enc(
    const float* __restrict__ A, const float* __restrict__ Bw,
    const float* __restrict__ bias, float* __restrict__ C, int K, int N) {
  __shared__ float As[16][132];
  __shared__ float Bs[16][68];
  const int tid = threadIdx.x;
  const int m0 = blockIdx.x << 7;
  const int n0 = blockIdx.y << 6;
  const int rr = tid >> 4;      // 16 row-groups of 8
  const int cc = tid & 15;      // 16 col-groups of 4
  float acc[8][4];
#pragma unroll
  for (int i = 0; i < 8; i++)
#pragma unroll
    for (int j = 0; j < 4; j++) acc[i][j] = 0.f;

  const int ar = tid >> 2;
  const int akq = (tid & 3) << 2;
  const int bk = tid >> 4;
  const int bn = (tid & 15) << 2;

  for (int k0 = 0; k0 < K; k0 += 16) {
    // stage A (128x16, transposed into As[k][m])
#pragma unroll
    for (int p = 0; p < 2; p++) {
      int m = m0 + ar + (p << 6);
      float4 v;
      if (AMODE == 1) v = e1_fetch(A, m, k0 + akq);
      else            v = *(const float4*)(A + (size_t)m * K + k0 + akq);
      As[akq + 0][ar + (p << 6)] = v.x;
      As[akq + 1][ar + (p << 6)] = v.y;
      As[akq + 2][ar + (p << 6)] = v.z;
      As[akq + 3][ar + (p << 6)] = v.w;
    }
    // stage B (16x64)
    {
      float4 v; v.x = v.y = v.z = v.w = 0.f;
      if ((k0 + bk) < K && (n0 + bn) < N)
        v = *(const float4*)(Bw + (size_t)(k0 + bk) * N + n0 + bn);
      *(float4*)&Bs[bk][bn] = v;
    }
    __syncthreads();
#pragma unroll
    for (int kk = 0; kk < 16; kk++) {
      float a[8], b4[4];
      *(float4*)&a[0] = *(const float4*)&As[kk][rr << 3];
      *(float4*)&a[4] = *(const float4*)&As[kk][(rr << 3) + 4];
      *(float4*)&b4[0] = *(const float4*)&Bs[kk][cc << 2];
#pragma unroll
      for (int i = 0; i < 8; i++)
#pragma unroll
        for (int j = 0; j < 4; j++) acc[i][j] += a[i] * b4[j];
    }
    __syncthreads();
  }

  // epilogue
  if (!SCATTER) {
#pragma unroll
    for (int i = 0; i < 8; i++) {
      int m = m0 + (rr << 3) + i;
      int n = n0 + (cc << 2);
      if (n + 3 < N) {
        float4 o;
        o.x = acc[i][0] + bias[n + 0];
        o.y = acc[i][1] + bias[n + 1];
        o.z = acc[i][2] + bias[n + 2];
        o.w = acc[i][3] + bias[n + 3];
        if (RELU) {
          o.x = fmaxf(o.x, 0.f); o.y = fmaxf(o.y, 0.f);
          o.z = fmaxf(o.z, 0.f); o.w = fmaxf(o.w, 0.f);
        }
        *(float4*)(C + (size_t)m * N + n) = o;
      } else {
#pragma unroll
        for (int j = 0; j < 4; j++) {
          if (n + j < N) {
            float v = acc[i][j] + bias[n + j];
            if (RELU) v = fmaxf(v, 0.f);
            C[(size_t)m * N + n + j] = v;
          }
        }
      }
    }
  } else {
    // controls: C_gemm[m][f] -> ctrl[t][f][b],  m = b*256 + t
#pragma unroll
    for (int i = 0; i < 8; i++) {
      int m = m0 + (rr << 3) + i;
      int t = m & 255, b = m >> 8;
#pragma unroll
      for (int j = 0; j < 4; j++) {
        int n = n0 + (cc << 2) + j;
        if (n < EN3) C[((size_t)t * EN3 + n) * BB + b] = acc[i][j] + bias[n];
      }
    }
  }
}

// ---------------------------------------------------------------------------
// decoder helpers
__device__ inline void dec_stage(float* __restrict__ dst, const float* __restrict__ src,
                                 int len, bool dorelu) {
  for (int idx = threadIdx.x; idx < (len << 4); idx += 256) {
    int kk = idx >> 4, j4 = (idx & 15) << 2;
    float4 v = *(const float4*)(src + ((size_t)kk << 6) + j4);
    if (dorelu) {
      v.x = fmaxf(v.x, 0.f); v.y = fmaxf(v.y, 0.f);
      v.z = fmaxf(v.z, 0.f); v.w = fmaxf(v.w, 0.f);
    }
    *(float4*)(dst + kk * 68 + j4) = v;
  }
}

__device__ inline void dec_preload(float* __restrict__ dst, const float* __restrict__ W,
                                   int row0, int len, int c0, int N, int ldw) {
  for (int idx = threadIdx.x; idx < (len << 6); idx += 256) {
    int kk = idx >> 6, j = idx & 63;
    int c = c0 + j;
    dst[kk * 68 + j] = (c < N) ? W[(size_t)(row0 + kk) * ldw + c] : 0.f;
  }
}

__device__ inline void dec_mac(float acc[4][4], const float* __restrict__ a,
                               const float* __restrict__ wl, int len, int rr, int cc) {
#pragma unroll 4
  for (int kk = 0; kk < len; kk++) {
    float4 av = *(const float4*)(a + kk * 68 + (rr << 2));
    float4 wv = *(const float4*)(wl + kk * 68 + (cc << 2));
    float aa[4] = {av.x, av.y, av.z, av.w};
    float ww[4] = {wv.x, wv.y, wv.z, wv.w};
#pragma unroll
    for (int i = 0; i < 4; i++)
#pragma unroll
      for (int j = 0; j < 4; j++) acc[i][j] += aa[i] * ww[j];
  }
}

__device__ inline void dec_epi(float acc[4][4], float* __restrict__ dst, int ct, int N,
                               const float* __restrict__ bias, int rr, int cc) {
#pragma unroll
  for (int j = 0; j < 4; j++) {
    int c = (ct << 6) + (cc << 2) + j;
    if (c < N) {
      float bv = bias ? bias[c] : 0.f;
#pragma unroll
      for (int i = 0; i < 4; i++) {
        int r = (rr << 2) + i;
        unsafeAtomicAdd(dst + ((size_t)c << 6) + r, acc[i][j] + bv);
      }
    }
  }
}

// sense-free generation barrier over 256 workgroups. bar[0]=count, bar[1]=gen
__device__ inline void gbar(unsigned* __restrict__ bar, unsigned target) {
  __syncthreads();
  if (threadIdx.x == 0) {
    __threadfence();
    unsigned prev = __hip_atomic_fetch_add(&bar[0], 1u, __ATOMIC_ACQ_REL, __HIP_MEMORY_SCOPE_AGENT);
    if (prev == 255u) {
      __hip_atomic_store(&bar[0], 0u, __ATOMIC_RELAXED, __HIP_MEMORY_SCOPE_AGENT);
      __hip_atomic_store(&bar[1], target, __ATOMIC_RELEASE, __HIP_MEMORY_SCOPE_AGENT);
    } else {
      unsigned g;
      do {
        g = __hip_atomic_load(&bar[1], __ATOMIC_ACQUIRE, __HIP_MEMORY_SCOPE_AGENT);
        if (g < target) __builtin_amdgcn_s_sleep(2);
      } while (g < target);
    }
    __threadfence();
  }
  __syncthreads();
}

// ---------------------------------------------------------------------------
// Persistent decoder. grid = 256 wgs x 256 thr (1 wg/CU).
// L1/L2: tiles (ct 0..16) x (ks 0..14), 255 wgs; L3: (ct 0..15) x (ks 0..15), 256 wgs.
// LDS: weight slices for all three layers, resident over all 256 steps.
__global__ __launch_bounds__(256, 1) void decoder_kernel(
    const float* __restrict__ W1, const float* __restrict__ b1,
    const float* __restrict__ W2, const float* __restrict__ b2,
    const float* __restrict__ W3, const float* __restrict__ b3,
    const float* __restrict__ ctrl, float* __restrict__ recon,
    float* __restrict__ h1, float* __restrict__ h2, unsigned* __restrict__ bar) {
  extern __shared__ float smem[];
  float* wsl1 = smem;               // 71*68
  float* wctl = wsl1 + 71 * 68;     // 33*68 (slice-0 only: ctrl rows + t-row)
  float* wsl2 = wctl + 33 * 68;     // 70*68
  float* wsl3 = wsl2 + 70 * 68;     // 65*68
  float* actl = wsl3 + 65 * 68;     // 71*68
  float* actc = actl + 71 * 68;     // 33*68

  const int w = blockIdx.x, tid = threadIdx.x;
  const int rr = tid >> 4, cc = tid & 15;

  const bool activeA = (w < 255);
  const int ctA = w / 15, ksA = w % 15;   // L1/L2 tile
  const int ctB = w >> 4, ksB = w & 15;   // L3 tile

  // L1 K-slices over the prev-segment (1024): slice0 = 30 rows (+33 ctrl/t rows), rest 71
  const int p_base = (ksA == 0) ? 0 : 30 + (ksA - 1) * 71;
  const int p_len  = (ksA == 0) ? 30 : 71;
  const int b2_ = ksA * 70;
  const int l2_ = min(70, DN1 - b2_);
  const int b3_ = ksB * 65;
  const int l3_ = min(65, DN2 - b3_);

  if (activeA) {
    dec_preload(wsl1, W1, 32 + p_base, p_len, ctA << 6, DN1, DN1);
    if (ksA == 0) {
      dec_preload(wctl, W1, 0, 32, ctA << 6, DN1, DN1);
      if (tid < 64) {
        int c = (ctA << 6) + tid;
        wctl[32 * 68 + tid] = (c < DN1) ? W1[(size_t)1056 * DN1 + c] : 0.f;  // t-row
      }
    }
    dec_preload(wsl2, W2, b2_, l2_, ctA << 6, DN2, DN2);
  }
  dec_preload(wsl3, W3, b3_, l3_, ctB << 6, DN3, DN3);

  unsigned gen = 0;

  for (int t = 0; t < TT; t++) {
    const int par = t & 1;
    gbar(bar, ++gen);  // also covers first-iteration preload visibility (block-local via its syncthreads)

    // ---------------- L1: comb -> h1[par] ----------------
    if (activeA) {
      dec_stage(actl, recon + ((size_t)t * DN3 + p_base) * 64, p_len, false);
      if (ksA == 0) {
        dec_stage(actc, ctrl + (size_t)t * EN3 * 64, 32, false);
        if (tid < 64) actc[32 * 68 + tid] = (float)t * (1.f / 256.f);
      }
      __syncthreads();
      float acc[4][4];
#pragma unroll
      for (int i = 0; i < 4; i++)
#pragma unroll
        for (int j = 0; j < 4; j++) acc[i][j] = 0.f;
      dec_mac(acc, actl, wsl1, p_len, rr, cc);
      if (ksA == 0) dec_mac(acc, actc, wctl, 33, rr, cc);
      dec_epi(acc, h1 + (size_t)par * DN1 * 64, ctA, DN1, (ksA == 0) ? b1 : nullptr, rr, cc);
    }
    gbar(bar, ++gen);

    // ---------------- L2: relu(h1[par]) -> h2[par]; zero h1[1-par] ----------------
    if (activeA) {
      dec_stage(actl, h1 + ((size_t)par * DN1 + b2_) * 64, l2_, true);
      __syncthreads();
      float acc[4][4];
#pragma unroll
      for (int i = 0; i < 4; i++)
#pragma unroll
        for (int j = 0; j < 4; j++) acc[i][j] = 0.f;
      dec_mac(acc, actl, wsl2, l2_, rr, cc);
      dec_epi(acc, h2 + (size_t)par * DN2 * 64, ctA, DN2, (ksA == 0) ? b2 : nullptr, rr, cc);
    }
    {
      float* z = h1 + (size_t)(1 - par) * DN1 * 64;
      int i = (w << 8) + tid;
      z[i < DN1 * 64 ? i : 0] = (i < DN1 * 64) ? 0.f : z[0];  // safe write below instead
    }
    // (clean form of the zeroing above)
    {
      float* z = h1 + (size_t)(1 - par) * DN1 * 64;
      int i = (w << 8) + tid;
      if (i < DN1 * 64) z[i] = 0.f;
      int i2 = i + 65536;
      if (i2 < DN1 * 64) z[i2] = 0.f;
    }
    gbar(bar, ++gen);

    // ---------------- L3: relu(h2[par]) -> recon[t+1]; zero h2[1-par] ----------------
    {
      dec_stage(actl, h2 + ((size_t)par * DN2 + b3_) * 64, l3_, true);
      __syncthreads();
      float acc[4][4];
#pragma unroll
      for (int i = 0; i < 4; i++)
#pragma unroll
        for (int j = 0; j < 4; j++) acc[i][j] = 0.f;
      dec_mac(acc, actl, wsl3, l3_, rr, cc);
      dec_epi(acc, recon + (size_t)(t + 1) * DN3 * 64, ctB, DN3, (ksB == 0) ? b3 : nullptr, rr, cc);
    }
    {
      float* z = h2 + (size_t)(1 - par) * DN2 * 64;
      int i = (w << 8) + tid;
      if (i < DN2 * 64) z[i] = 0.f;
      int i2 = i + 65536;
      if (i2 < DN2 * 64) z[i2] = 0.f;
    }
  }
}

// recon[t+1][s][b] -> out[b][s][t]
__global__ void permute_out(const float* __restrict__ recon, float* __restrict__ out) {
  __shared__ float tl[32][65];
  int s = blockIdx.x;
  int t0 = blockIdx.y << 5;
  int tid = threadIdx.x;
  int b = tid & 63, tq = tid >> 6;
#pragma unroll
  for (int i = 0; i < 8; i++) {
    int tt = (tq << 3) + i;
    tl[tt][b] = recon[((size_t)(t0 + tt + 1) * SS + s) * 64 + b];
  }
  __syncthreads();
  int k = tid & 31, bq = tid >> 5;
#pragma unroll
  for (int i = 0; i < 8; i++) {
    int bb = (bq << 3) + i;
    out[((size_t)bb * SS + s) * TT + t0 + k] = tl[k][bb];
  }
}

// ---------------------------------------------------------------------------
extern "C" void kernel_launch(void* const* d_in, const int* in_sizes, int n_in,
                              void* d_out, int out_size, void* d_ws, size_t ws_size,
                              hipStream_t stream) {
  (void)in_sizes; (void)n_in; (void)out_size; (void)ws_size;
  const float* x   = (const float*)d_in[0];
  const float* eW1 = (const float*)d_in[1];
  const float* eb1 = (const float*)d_in[2];
  const float* eW2 = (const float*)d_in[3];
  const float* eb2 = (const float*)d_in[4];
  const float* eW3 = (const float*)d_in[5];
  const float* eb3 = (const float*)d_in[6];
  const float* dW1 = (const float*)d_in[7];
  const float* db1 = (const float*)d_in[8];
  const float* dW2 = (const float*)d_in[9];
  const float* db2 = (const float*)d_in[10];
  const float* dW3 = (const float*)d_in[11];
  const float* db3 = (const float*)d_in[12];

  float* ws   = (float*)d_ws;
  float* xt   = ws + OFF_XT;
  float* e1p  = ws + OFF_E1;
  float* e2p  = ws + OFF_E2;
  float* ctrlp = ws + OFF_CTRL;
  float* reconp = ws + OFF_RECON;
  float* h1p  = ws + OFF_H1;
  float* h2p  = ws + OFF_H2;
  unsigned* barp = (unsigned*)(ws + OFF_BAR);

  // zero recon/h1/h2/barrier (contiguous span) — required every launch (ws re-poisoned)
  zero_init<<<dim3(4096), dim3(256), 0, stream>>>(ws + OFF_RECON, ZERO_N);

  transpose_x<<<dim3(32, 8, 64), dim3(256), 0, stream>>>(x, xt);

  // encoder
  gemm_enc<1, true,  false><<<dim3(128, 15), dim3(256), 0, stream>>>(xt,  eW1, eb1, e1p, EK1, EN1);
  gemm_enc<0, true,  false><<<dim3(128, 7),  dim3(256), 0, stream>>>(e1p, eW2, eb2, e2p, EN1, EN2);
  gemm_enc<0, false, true ><<<dim3(128, 1),  dim3(256), 0, stream>>>(e2p, eW3, eb3, ctrlp, EN2, EN3);

  // decoder (persistent cooperative)
  hipFuncSetAttribute((const void*)decoder_kernel,
                      hipFuncAttributeMaxDynamicSharedMemorySize, DEC_SMEM);
  const float *a0 = dW1, *a1 = db1, *a2 = dW2, *a3 = db2, *a4 = dW3, *a5 = db3, *a6 = ctrlp;
  float *r0 = reconp, *r1 = h1p, *r2 = h2p;
  unsigned* r3 = barp;
  void* kargs[] = {&a0, &a1, &a2, &a3, &a4, &a5, &a6, &r0, &r1, &r2, &r3};
  hipLaunchCooperativeKernel((void*)decoder_kernel, dim3(256), dim3(256), kargs,
                             DEC_SMEM, stream);

  permute_out<<<dim3(1024, 8), dim3(256), 0, stream>>>(reconp, (float*)d_out);
}

// Round 2
// 26983.560 us; speedup vs baseline: 1.4623x; 1.4623x over previous
//
#include <hip/hip_runtime.h>
#include <cstdint>
#include <cstddef>

// ---------------------------------------------------------------------------
// StepWiseMLPAutoEncoder  (MI355X / gfx950)  — round 2: fixed-coherence sync
//   Round-1 pathology: ACQUIRE-agent polling emitted buffer_inv (L1+L2 inv)
//   per poll iteration -> 50us/barrier. Now: relaxed monotonic barrier +
//   ONE acquire-agent fence per phase; all cross-wg writes are agent-scope
//   atomics (LLC write-through, L2 never dirty).
// ---------------------------------------------------------------------------

#define TT 256
#define BB 64
#define SS 1024
#define MROWS 16384

#define EK1 2049
#define EN1 944
#define EN2 416
#define EN3 32

#define DK1 1057
#define DN1 1046
#define DN2 1035
#define DN3 1024

// ws layout (float offsets). Total = 56,692,880 floats = ~216 MiB.
#define OFF_XT    ((size_t)0)
#define OFF_E1    ((size_t)16777216)                 // 16384*1024
#define OFF_E2    ((size_t)(OFF_E1 + 15466496))      // 16384*944
#define OFF_CTRL  ((size_t)(OFF_E2 + 6815744))       // 16384*416
#define OFF_RECON ((size_t)(OFF_CTRL + 524288))      // 256*32*64
#define OFF_H1    ((size_t)(OFF_RECON + 16842752))   // 257*1024*64
#define OFF_H2    ((size_t)(OFF_H1 + 133888))        // 2*1046*64
#define OFF_BAR   ((size_t)(OFF_H2 + 132480))        // 2*1035*64
#define ZERO_N    ((size_t)(16842752 + 133888 + 132480 + 16))

#define DEC_SMEM (343*68*4)   // 93,296 B dynamic LDS for decoder

// ---------------------------------------------------------------------------
__global__ void zero_init(float* __restrict__ p, size_t n) {
  size_t i = (size_t)blockIdx.x * blockDim.x + threadIdx.x;
  size_t stride = (size_t)gridDim.x * blockDim.x;
  for (; i < n; i += stride) p[i] = 0.f;
}

// x[b][s][t] -> xt[b][t][s]
__global__ void transpose_x(const float* __restrict__ x, float* __restrict__ xt) {
  __shared__ float tile[32][33];
  int b = blockIdx.z;
  int s0 = blockIdx.x << 5;   // S/32 = 32 tiles
  int t0 = blockIdx.y << 5;   // T/32 = 8 tiles
  int lt = threadIdx.x & 31;
  int ls = threadIdx.x >> 5;  // 0..7
  const float* xp = x + (size_t)b * SS * TT;
#pragma unroll
  for (int i = 0; i < 4; i++) {
    int s = s0 + ls + (i << 3);
    tile[ls + (i << 3)][lt] = xp[(size_t)s * TT + t0 + lt];
  }
  __syncthreads();
  float* xtp = xt + (size_t)b * TT * SS;
#pragma unroll
  for (int i = 0; i < 4; i++) {
    int t = t0 + ls + (i << 3);
    xtp[(size_t)t * SS + s0 + lt] = tile[lt][ls + (i << 3)];
  }
}

// virtual A for encoder layer 1: row m=(b,t), k: [prev(1024) | cur(1024) | t/T | pad]
__device__ inline float4 e1_fetch(const float* __restrict__ xt, int m, int kg) {
  float4 z; z.x = z.y = z.z = z.w = 0.f;
  int t = m & 255;
  if (kg < 1024) {
    if (t == 0) return z;
    return *(const float4*)(xt + (((size_t)(m - 1)) << 10) + kg);
  } else if (kg < 2048) {
    return *(const float4*)(xt + (((size_t)m) << 10) + (kg - 1024));
  } else if (kg == 2048) {
    z.x = (float)t * (1.0f / 256.0f);
    return z;
  }
  return z;
}

// ---------------------------------------------------------------------------
// Tiled fp32 GEMM: C[M][N] = act(A[M][K] @ B[K][N] + bias). BM=128 BN=64 BK=16.
template <int AMODE, bool RELU, bool SCATTER>
__global__ __launch_bounds__(256, 2) void gemm_enc(
    const float* __restrict__ A, const float* __restrict__ Bw,
    const float* __restrict__ bias, float* __restrict__ C, int K, int N) {
  __shared__ float As[16][132];
  __shared__ float Bs[16][68];
  const int tid = threadIdx.x;
  const int m0 = blockIdx.x << 7;
  const int n0 = blockIdx.y << 6;
  const int rr = tid >> 4;      // 16 row-groups of 8
  const int cc = tid & 15;      // 16 col-groups of 4
  float acc[8][4];
#pragma unroll
  for (int i = 0; i < 8; i++)
#pragma unroll
    for (int j = 0; j < 4; j++) acc[i][j] = 0.f;

  const int ar = tid >> 2;
  const int akq = (tid & 3) << 2;
  const int bk = tid >> 4;
  const int bn = (tid & 15) << 2;

  for (int k0 = 0; k0 < K; k0 += 16) {
#pragma unroll
    for (int p = 0; p < 2; p++) {
      int m = m0 + ar + (p << 6);
      float4 v;
      if (AMODE == 1) v = e1_fetch(A, m, k0 + akq);
      else            v = *(const float4*)(A + (size_t)m * K + k0 + akq);
      As[akq + 0][ar + (p << 6)] = v.x;
      As[akq + 1][ar + (p << 6)] = v.y;
      As[akq + 2][ar + (p << 6)] = v.z;
      As[akq + 3][ar + (p << 6)] = v.w;
    }
    {
      float4 v; v.x = v.y = v.z = v.w = 0.f;
      if ((k0 + bk) < K && (n0 + bn) < N)
        v = *(const float4*)(Bw + (size_t)(k0 + bk) * N + n0 + bn);
      *(float4*)&Bs[bk][bn] = v;
    }
    __syncthreads();
#pragma unroll
    for (int kk = 0; kk < 16; kk++) {
      float a[8], b4[4];
      *(float4*)&a[0] = *(const float4*)&As[kk][rr << 3];
      *(float4*)&a[4] = *(const float4*)&As[kk][(rr << 3) + 4];
      *(float4*)&b4[0] = *(const float4*)&Bs[kk][cc << 2];
#pragma unroll
      for (int i = 0; i < 8; i++)
#pragma unroll
        for (int j = 0; j < 4; j++) acc[i][j] += a[i] * b4[j];
    }
    __syncthreads();
  }

  if (!SCATTER) {
#pragma unroll
    for (int i = 0; i < 8; i++) {
      int m = m0 + (rr << 3) + i;
      int n = n0 + (cc << 2);
      if (n + 3 < N) {
        float4 o;
        o.x = acc[i][0] + bias[n + 0];
        o.y = acc[i][1] + bias[n + 1];
        o.z = acc[i][2] + bias[n + 2];
        o.w = acc[i][3] + bias[n + 3];
        if (RELU) {
          o.x = fmaxf(o.x, 0.f); o.y = fmaxf(o.y, 0.f);
          o.z = fmaxf(o.z, 0.f); o.w = fmaxf(o.w, 0.f);
        }
        *(float4*)(C + (size_t)m * N + n) = o;
      } else {
#pragma unroll
        for (int j = 0; j < 4; j++) {
          if (n + j < N) {
            float v = acc[i][j] + bias[n + j];
            if (RELU) v = fmaxf(v, 0.f);
            C[(size_t)m * N + n + j] = v;
          }
        }
      }
    }
  } else {
    // controls: C_gemm[m][f] -> ctrl[t][f][b],  m = b*256 + t
#pragma unroll
    for (int i = 0; i < 8; i++) {
      int m = m0 + (rr << 3) + i;
      int t = m & 255, b = m >> 8;
#pragma unroll
      for (int j = 0; j < 4; j++) {
        int n = n0 + (cc << 2) + j;
        if (n < EN3) C[((size_t)t * EN3 + n) * BB + b] = acc[i][j] + bias[n];
      }
    }
  }
}

// ---------------------------------------------------------------------------
// decoder helpers
__device__ inline void dec_stage(float* __restrict__ dst, const float* __restrict__ src,
                                 int len, bool dorelu) {
  for (int idx = threadIdx.x; idx < (len << 4); idx += 256) {
    int kk = idx >> 4, j4 = (idx & 15) << 2;
    float4 v = *(const float4*)(src + ((size_t)kk << 6) + j4);
    if (dorelu) {
      v.x = fmaxf(v.x, 0.f); v.y = fmaxf(v.y, 0.f);
      v.z = fmaxf(v.z, 0.f); v.w = fmaxf(v.w, 0.f);
    }
    *(float4*)(dst + kk * 68 + j4) = v;
  }
}

__device__ inline void dec_preload(float* __restrict__ dst, const float* __restrict__ W,
                                   int row0, int len, int c0, int N, int ldw) {
  for (int idx = threadIdx.x; idx < (len << 6); idx += 256) {
    int kk = idx >> 6, j = idx & 63;
    int c = c0 + j;
    dst[kk * 68 + j] = (c < N) ? W[(size_t)(row0 + kk) * ldw + c] : 0.f;
  }
}

__device__ inline void dec_mac(float acc[4][4], const float* __restrict__ a,
                               const float* __restrict__ wl, int len, int rr, int cc) {
#pragma unroll 4
  for (int kk = 0; kk < len; kk++) {
    float4 av = *(const float4*)(a + kk * 68 + (rr << 2));
    float4 wv = *(const float4*)(wl + kk * 68 + (cc << 2));
    float aa[4] = {av.x, av.y, av.z, av.w};
    float ww[4] = {wv.x, wv.y, wv.z, wv.w};
#pragma unroll
    for (int i = 0; i < 4; i++)
#pragma unroll
      for (int j = 0; j < 4; j++) acc[i][j] += aa[i] * ww[j];
  }
}

__device__ inline void dec_epi(float acc[4][4], float* __restrict__ dst, int ct, int N,
                               const float* __restrict__ bias, int rr, int cc) {
#pragma unroll
  for (int j = 0; j < 4; j++) {
    int c = (ct << 6) + (cc << 2) + j;
    if (c < N) {
      float bv = bias ? bias[c] : 0.f;
#pragma unroll
      for (int i = 0; i < 4; i++) {
        int r = (rr << 2) + i;
        unsafeAtomicAdd(dst + ((size_t)c << 6) + r, acc[i][j] + bv);
      }
    }
  }
}

__device__ inline void zero_agent(float* __restrict__ z, int n, int w) {
  for (int i = (w << 8) + (int)threadIdx.x; i < n; i += 65536)
    __hip_atomic_store(z + i, 0.f, __ATOMIC_RELAXED, __HIP_MEMORY_SCOPE_AGENT);
}

// ---------------------------------------------------------------------------
// Relaxed monotonic global barrier over 256 workgroups.
// - __syncthreads() drains each wave's vmem (HIP emits s_waitcnt vmcnt(0)
//   before s_barrier), so all atomics of this wg are at the coherence point
//   before the arrive.
// - Arrive + poll are RELAXED agent-scope (no buffer_inv per poll!).
// - ONE acquire-agent fence per barrier (L1+L2 invalidate) so subsequent
//   plain cached loads see LLC-fresh data.
// target must be gen*256 with gen monotonically increasing. Max skew between
// wgs is one barrier, so a monotone >= test is exact.
__device__ inline void gbar(unsigned* __restrict__ bar, unsigned target) {
  __syncthreads();
  if (threadIdx.x == 0) {
    asm volatile("s_waitcnt vmcnt(0)" ::: "memory");
    __hip_atomic_fetch_add(bar, 1u, __ATOMIC_RELAXED, __HIP_MEMORY_SCOPE_AGENT);
    while (__hip_atomic_load(bar, __ATOMIC_RELAXED, __HIP_MEMORY_SCOPE_AGENT) < target)
      __builtin_amdgcn_s_sleep(2);
  }
  __syncthreads();
  __builtin_amdgcn_fence(__ATOMIC_ACQUIRE, "agent");
}

// ---------------------------------------------------------------------------
// Persistent decoder. grid = 256 wgs x 256 thr (1 wg/CU).
__global__ __launch_bounds__(256, 1) void decoder_kernel(
    const float* __restrict__ W1, const float* __restrict__ b1,
    const float* __restrict__ W2, const float* __restrict__ b2,
    const float* __restrict__ W3, const float* __restrict__ b3,
    const float* __restrict__ ctrl, float* __restrict__ recon,
    float* __restrict__ h1, float* __restrict__ h2, unsigned* __restrict__ bar) {
  extern __shared__ float smem[];
  float* wsl1 = smem;               // 71*68
  float* wctl = wsl1 + 71 * 68;     // 33*68 (slice-0 only: ctrl rows + t-row)
  float* wsl2 = wctl + 33 * 68;     // 70*68
  float* wsl3 = wsl2 + 70 * 68;     // 65*68
  float* actl = wsl3 + 65 * 68;     // 71*68
  float* actc = actl + 71 * 68;     // 33*68

  const int w = blockIdx.x, tid = threadIdx.x;
  const int rr = tid >> 4, cc = tid & 15;

  const bool activeA = (w < 255);
  const int ctA = w / 15, ksA = w % 15;   // L1/L2 tile
  const int ctB = w >> 4, ksB = w & 15;   // L3 tile

  const int p_base = (ksA == 0) ? 0 : 30 + (ksA - 1) * 71;
  const int p_len  = (ksA == 0) ? 30 : 71;
  const int b2_ = ksA * 70;
  const int l2_ = min(70, DN1 - b2_);
  const int b3_ = ksB * 65;
  const int l3_ = min(65, DN2 - b3_);

  if (activeA) {
    dec_preload(wsl1, W1, 32 + p_base, p_len, ctA << 6, DN1, DN1);
    if (ksA == 0) {
      dec_preload(wctl, W1, 0, 32, ctA << 6, DN1, DN1);
      if (tid < 64) {
        int c = (ctA << 6) + tid;
        wctl[32 * 68 + tid] = (c < DN1) ? W1[(size_t)1056 * DN1 + c] : 0.f;  // t-row
      }
    }
    dec_preload(wsl2, W2, b2_, l2_, ctA << 6, DN2, DN2);
  }
  dec_preload(wsl3, W3, b3_, l3_, ctB << 6, DN3, DN3);

  unsigned gen = 0;

  for (int t = 0; t < TT; t++) {
    const int par = t & 1;
    gen++; gbar(bar, gen << 8);

    // ---------------- L1: comb -> h1[par] ----------------
    if (activeA) {
      dec_stage(actl, recon + ((size_t)t * DN3 + p_base) * 64, p_len, false);
      if (ksA == 0) {
        dec_stage(actc, ctrl + (size_t)t * EN3 * 64, 32, false);
        if (tid < 64) actc[32 * 68 + tid] = (float)t * (1.f / 256.f);
      }
      __syncthreads();
      float acc[4][4];
#pragma unroll
      for (int i = 0; i < 4; i++)
#pragma unroll
        for (int j = 0; j < 4; j++) acc[i][j] = 0.f;
      dec_mac(acc, actl, wsl1, p_len, rr, cc);
      if (ksA == 0) dec_mac(acc, actc, wctl, 33, rr, cc);
      dec_epi(acc, h1 + (size_t)par * DN1 * 64, ctA, DN1, (ksA == 0) ? b1 : nullptr, rr, cc);
    }
    gen++; gbar(bar, gen << 8);

    // ---------------- L2: relu(h1[par]) -> h2[par]; zero h1[1-par] ----------------
    if (activeA) {
      dec_stage(actl, h1 + ((size_t)par * DN1 + b2_) * 64, l2_, true);
      __syncthreads();
      float acc[4][4];
#pragma unroll
      for (int i = 0; i < 4; i++)
#pragma unroll
        for (int j = 0; j < 4; j++) acc[i][j] = 0.f;
      dec_mac(acc, actl, wsl2, l2_, rr, cc);
      dec_epi(acc, h2 + (size_t)par * DN2 * 64, ctA, DN2, (ksA == 0) ? b2 : nullptr, rr, cc);
    }
    zero_agent(h1 + (size_t)(1 - par) * DN1 * 64, DN1 * 64, w);
    gen++; gbar(bar, gen << 8);

    // ---------------- L3: relu(h2[par]) -> recon[t+1]; zero h2[1-par] ----------------
    {
      dec_stage(actl, h2 + ((size_t)par * DN2 + b3_) * 64, l3_, true);
      __syncthreads();
      float acc[4][4];
#pragma unroll
      for (int i = 0; i < 4; i++)
#pragma unroll
        for (int j = 0; j < 4; j++) acc[i][j] = 0.f;
      dec_mac(acc, actl, wsl3, l3_, rr, cc);
      dec_epi(acc, recon + (size_t)(t + 1) * DN3 * 64, ctB, DN3, (ksB == 0) ? b3 : nullptr, rr, cc);
    }
    zero_agent(h2 + (size_t)(1 - par) * DN2 * 64, DN2 * 64, w);
  }
}

// recon[t+1][s][b] -> out[b][s][t]
__global__ void permute_out(const float* __restrict__ recon, float* __restrict__ out) {
  __shared__ float tl[32][65];
  int s = blockIdx.x;
  int t0 = blockIdx.y << 5;
  int tid = threadIdx.x;
  int b = tid & 63, tq = tid >> 6;
#pragma unroll
  for (int i = 0; i < 8; i++) {
    int tt = (tq << 3) + i;
    tl[tt][b] = recon[((size_t)(t0 + tt + 1) * SS + s) * 64 + b];
  }
  __syncthreads();
  int k = tid & 31, bq = tid >> 5;
#pragma unroll
  for (int i = 0; i < 8; i++) {
    int bb = (bq << 3) + i;
    out[((size_t)bb * SS + s) * TT + t0 + k] = tl[k][bb];
  }
}

// ---------------------------------------------------------------------------
extern "C" void kernel_launch(void* const* d_in, const int* in_sizes, int n_in,
                              void* d_out, int out_size, void* d_ws, size_t ws_size,
                              hipStream_t stream) {
  (void)in_sizes; (void)n_in; (void)out_size; (void)ws_size;
  const float* x   = (const float*)d_in[0];
  const float* eW1 = (const float*)d_in[1];
  const float* eb1 = (const float*)d_in[2];
  const float* eW2 = (const float*)d_in[3];
  const float* eb2 = (const float*)d_in[4];
  const float* eW3 = (const float*)d_in[5];
  const float* eb3 = (const float*)d_in[6];
  const float* dW1 = (const float*)d_in[7];
  const float* db1 = (const float*)d_in[8];
  const float* dW2 = (const float*)d_in[9];
  const float* db2 = (const float*)d_in[10];
  const float* dW3 = (const float*)d_in[11];
  const float* db3 = (const float*)d_in[12];

  float* ws   = (float*)d_ws;
  float* xt   = ws + OFF_XT;
  float* e1p  = ws + OFF_E1;
  float* e2p  = ws + OFF_E2;
  float* ctrlp = ws + OFF_CTRL;
  float* reconp = ws + OFF_RECON;
  float* h1p  = ws + OFF_H1;
  float* h2p  = ws + OFF_H2;
  unsigned* barp = (unsigned*)(ws + OFF_BAR);

  zero_init<<<dim3(4096), dim3(256), 0, stream>>>(ws + OFF_RECON, ZERO_N);

  transpose_x<<<dim3(32, 8, 64), dim3(256), 0, stream>>>(x, xt);

  gemm_enc<1, true,  false><<<dim3(128, 15), dim3(256), 0, stream>>>(xt,  eW1, eb1, e1p, EK1, EN1);
  gemm_enc<0, true,  false><<<dim3(128, 7),  dim3(256), 0, stream>>>(e1p, eW2, eb2, e2p, EN1, EN2);
  gemm_enc<0, false, true ><<<dim3(128, 1),  dim3(256), 0, stream>>>(e2p, eW3, eb3, ctrlp, EN2, EN3);

  hipFuncSetAttribute((const void*)decoder_kernel,
                      hipFuncAttributeMaxDynamicSharedMemorySize, DEC_SMEM);
  const float *a0 = dW1, *a1 = db1, *a2 = dW2, *a3 = db2, *a4 = dW3, *a5 = db3, *a6 = ctrlp;
  float *r0 = reconp, *r1 = h1p, *r2 = h2p;
  unsigned* r3 = barp;
  void* kargs[] = {&a0, &a1, &a2, &a3, &a4, &a5, &a6, &r0, &r1, &r2, &r3};
  hipLaunchCooperativeKernel((void*)decoder_kernel, dim3(256), dim3(256), kargs,
                             DEC_SMEM, stream);

  permute_out<<<dim3(1024, 8), dim3(256), 0, stream>>>(reconp, (float*)d_out);
}

// Round 3
// 22860.803 us; speedup vs baseline: 1.7260x; 1.1803x over previous
//
#include <hip/hip_runtime.h>
#include <cstdint>
#include <cstddef>

// ---------------------------------------------------------------------------
// StepWiseMLPAutoEncoder (MI355X/gfx950) — round 3: no-atomic decoder
//   Decomposition: wg = 4-5 output cols x full K. Complete outputs per wg ->
//   no cross-wg reduction, no atomics, no parity zeroing.
//   Activations quad-interleaved [k/4][batch][4] -> 1KB coalesced float4 loads.
//   Weights transposed WT[col][k] read via wave-uniform scalar loads.
//   Barrier: round-2 proven relaxed arrive/poll + one acquire fence.
// ---------------------------------------------------------------------------

#define TT 256
#define BB 64
#define SS 1024

#define EK1 2049
#define EN1 944
#define EN2 416
#define EN3 32

#define DN1 1046
#define DN2 1035
#define DN3 1024

// K paddings (quad-multiples) and padded WT row counts
#define KP1 1060   // 32 ctrl + 1024 prev + 1 t + 3 pad
#define KP2 1048   // 1046 + 2
#define KP3 1036   // 1035 + 1
#define NQ1 265
#define NQ2 262
#define NQ3 259
#define WROWS1 1048
#define WROWS2 1040
#define WROWS3 1028

// ws layout (float offsets)
#define OFF_XT    ((size_t)0)                        // 16,777,216 (xt; reused after E1)
#define OFF_WT1   ((size_t)0)                        //  1048*1060 = 1,110,880
#define OFF_WT2   ((size_t)1110880)                  //  1040*1048 = 1,089,920
#define OFF_WT3   ((size_t)2200800)                  //  1028*1036 = 1,065,008
#define OFF_H1    ((size_t)3265808)                  //  262*256 = 67,072
#define OFF_H2    ((size_t)3332880)                  //  259*256 = 66,304
#define OFF_E1    ((size_t)16777216)                 // 16384*944
#define OFF_E2    ((size_t)(OFF_E1 + 15466496))      // 16384*416
#define OFF_COMB  ((size_t)(OFF_E2 + 6815744))       // 257*265*256 = 17,434,880
#define OFF_BAR   ((size_t)(OFF_COMB + 17434880))    // 16
// total = OFF_BAR + 16 = 56,494,352 floats (~226 MB, <= round-1 footprint)

#define COMB_SLOT (265 * 256)

// ---------------------------------------------------------------------------
__global__ void zero_init(float* __restrict__ p, size_t n) {
  size_t i = (size_t)blockIdx.x * blockDim.x + threadIdx.x;
  size_t stride = (size_t)gridDim.x * blockDim.x;
  for (; i < n; i += stride) p[i] = 0.f;
}

// x[b][s][t] -> xt[b][t][s]
__global__ void transpose_x(const float* __restrict__ x, float* __restrict__ xt) {
  __shared__ float tile[32][33];
  int b = blockIdx.z;
  int s0 = blockIdx.x << 5;
  int t0 = blockIdx.y << 5;
  int lt = threadIdx.x & 31;
  int ls = threadIdx.x >> 5;
  const float* xp = x + (size_t)b * SS * TT;
#pragma unroll
  for (int i = 0; i < 4; i++) {
    int s = s0 + ls + (i << 3);
    tile[ls + (i << 3)][lt] = xp[(size_t)s * TT + t0 + lt];
  }
  __syncthreads();
  float* xtp = xt + (size_t)b * TT * SS;
#pragma unroll
  for (int i = 0; i < 4; i++) {
    int t = t0 + ls + (i << 3);
    xtp[(size_t)t * SS + s0 + lt] = tile[lt][ls + (i << 3)];
  }
}

// W[k][n] -> WT[c][k], zero-padded to KPAD cols / NCP rows
__global__ void transpose_w(const float* __restrict__ W, float* __restrict__ WT,
                            int K, int N, int KPAD, int NCP) {
  __shared__ float tl[32][33];
  int c0 = blockIdx.x << 5, k0 = blockIdx.y << 5;
  int lx = threadIdx.x & 31, ly = threadIdx.x >> 5;  // 0..7
#pragma unroll
  for (int i = 0; i < 4; i++) {
    int k = k0 + ly + (i << 3);
    int c = c0 + lx;
    tl[ly + (i << 3)][lx] = (k < K && c < N) ? W[(size_t)k * N + c] : 0.f;
  }
  __syncthreads();
#pragma unroll
  for (int i = 0; i < 4; i++) {
    int c = c0 + ly + (i << 3);
    int k = k0 + lx;
    if (c < NCP && k < KPAD) WT[(size_t)c * KPAD + k] = tl[lx][ly + (i << 3)];
  }
}

// comb[t][quad 264][r][0] = t/256, [1..3] = 0
__global__ void init_tail(float* __restrict__ comb) {
  int i = blockIdx.x * blockDim.x + threadIdx.x;  // 0..16383
  int t = i >> 6, r = i & 63;
  float4 v;
  v.x = (float)t * (1.f / 256.f);
  v.y = v.z = v.w = 0.f;
  *(float4*)(comb + ((size_t)t * 265 + 264) * 256 + (r << 2)) = v;
}

// virtual A for encoder layer 1: row m=(b,t), k: [prev(1024) | cur(1024) | t | pad]
__device__ inline float4 e1_fetch(const float* __restrict__ xt, int m, int kg) {
  float4 z; z.x = z.y = z.z = z.w = 0.f;
  int t = m & 255;
  if (kg < 1024) {
    if (t == 0) return z;
    return *(const float4*)(xt + (((size_t)(m - 1)) << 10) + kg);
  } else if (kg < 2048) {
    return *(const float4*)(xt + (((size_t)m) << 10) + (kg - 1024));
  } else if (kg == 2048) {
    z.x = (float)t * (1.0f / 256.0f);
    return z;
  }
  return z;
}

// ---------------------------------------------------------------------------
// Tiled fp32 GEMM: C[M][N] = act(A[M][K] @ B[K][N] + bias). BM=128 BN=64 BK=16.
// SCATTER epilogue writes ctrl into comb prefix: comb[t][n>>2][b][n&3].
template <int AMODE, bool RELU, bool SCATTER>
__global__ __launch_bounds__(256, 2) void gemm_enc(
    const float* __restrict__ A, const float* __restrict__ Bw,
    const float* __restrict__ bias, float* __restrict__ C, int K, int N) {
  __shared__ float As[16][132];
  __shared__ float Bs[16][68];
  const int tid = threadIdx.x;
  const int m0 = blockIdx.x << 7;
  const int n0 = blockIdx.y << 6;
  const int rr = tid >> 4;
  const int cc = tid & 15;
  float acc[8][4];
#pragma unroll
  for (int i = 0; i < 8; i++)
#pragma unroll
    for (int j = 0; j < 4; j++) acc[i][j] = 0.f;

  const int ar = tid >> 2;
  const int akq = (tid & 3) << 2;
  const int bk = tid >> 4;
  const int bn = (tid & 15) << 2;

  for (int k0 = 0; k0 < K; k0 += 16) {
#pragma unroll
    for (int p = 0; p < 2; p++) {
      int m = m0 + ar + (p << 6);
      float4 v;
      if (AMODE == 1) v = e1_fetch(A, m, k0 + akq);
      else            v = *(const float4*)(A + (size_t)m * K + k0 + akq);
      As[akq + 0][ar + (p << 6)] = v.x;
      As[akq + 1][ar + (p << 6)] = v.y;
      As[akq + 2][ar + (p << 6)] = v.z;
      As[akq + 3][ar + (p << 6)] = v.w;
    }
    {
      float4 v; v.x = v.y = v.z = v.w = 0.f;
      if ((k0 + bk) < K && (n0 + bn) < N)
        v = *(const float4*)(Bw + (size_t)(k0 + bk) * N + n0 + bn);
      *(float4*)&Bs[bk][bn] = v;
    }
    __syncthreads();
#pragma unroll
    for (int kk = 0; kk < 16; kk++) {
      float a[8], b4[4];
      *(float4*)&a[0] = *(const float4*)&As[kk][rr << 3];
      *(float4*)&a[4] = *(const float4*)&As[kk][(rr << 3) + 4];
      *(float4*)&b4[0] = *(const float4*)&Bs[kk][cc << 2];
#pragma unroll
      for (int i = 0; i < 8; i++)
#pragma unroll
        for (int j = 0; j < 4; j++) acc[i][j] += a[i] * b4[j];
    }
    __syncthreads();
  }

  if (!SCATTER) {
#pragma unroll
    for (int i = 0; i < 8; i++) {
      int m = m0 + (rr << 3) + i;
      int n = n0 + (cc << 2);
      if (n + 3 < N) {
        float4 o;
        o.x = acc[i][0] + bias[n + 0];
        o.y = acc[i][1] + bias[n + 1];
        o.z = acc[i][2] + bias[n + 2];
        o.w = acc[i][3] + bias[n + 3];
        if (RELU) {
          o.x = fmaxf(o.x, 0.f); o.y = fmaxf(o.y, 0.f);
          o.z = fmaxf(o.z, 0.f); o.w = fmaxf(o.w, 0.f);
        }
        *(float4*)(C + (size_t)m * N + n) = o;
      } else {
#pragma unroll
        for (int j = 0; j < 4; j++) {
          if (n + j < N) {
            float v = acc[i][j] + bias[n + j];
            if (RELU) v = fmaxf(v, 0.f);
            C[(size_t)m * N + n + j] = v;
          }
        }
      }
    }
  } else {
    // ctrl -> comb prefix: m = b*256 + t; comb[t][n>>2][b][n&3]
#pragma unroll
    for (int i = 0; i < 8; i++) {
      int m = m0 + (rr << 3) + i;
      int t = m & 255, b = m >> 8;
#pragma unroll
      for (int j = 0; j < 4; j++) {
        int n = n0 + (cc << 2) + j;
        if (n < EN3)
          C[((size_t)t * 265 + (n >> 2)) * 256 + (b << 2) + (n & 3)] = acc[i][j] + bias[n];
      }
    }
  }
}

// ---------------------------------------------------------------------------
// Relaxed monotonic global barrier over 256 wgs (round-2 proven).
__device__ inline void gbar(unsigned* __restrict__ bar, unsigned target) {
  __syncthreads();
  if (threadIdx.x == 0) {
    asm volatile("s_waitcnt vmcnt(0)" ::: "memory");
    __hip_atomic_fetch_add(bar, 1u, __ATOMIC_RELAXED, __HIP_MEMORY_SCOPE_AGENT);
    while (__hip_atomic_load(bar, __ATOMIC_RELAXED, __HIP_MEMORY_SCOPE_AGENT) < target)
      __builtin_amdgcn_s_sleep(2);
  }
  __syncthreads();
  __builtin_amdgcn_fence(__ATOMIC_ACQUIRE, "agent");
}

// ---------------------------------------------------------------------------
// One decoder layer phase. actb quad-interleaved [quad][64 r][4]. wt = WT[c][KPAD]
// (rows padded so reading 5 rows is always safe). Output written quad-interleaved
// at column offset outk_off + colbase.
template <int NQ, int KPAD, bool RELU>
__device__ inline void dec_phase(const float* __restrict__ actb,
                                 const float* __restrict__ wt,
                                 const float* __restrict__ bias,
                                 float* __restrict__ outb, int outk_off,
                                 int nc, int colbase, int r, int q,
                                 float* __restrict__ red, int tid) {
  float a0 = 0.f, a1 = 0.f, a2 = 0.f, a3 = 0.f, a4 = 0.f;
  const float* w0 = wt + (size_t)colbase * KPAD;
#pragma unroll 4
  for (int j = q; j < NQ; j += 8) {
    float4 av = *(const float4*)(actb + (j << 8) + (r << 2));
    const float* wq = w0 + (j << 2);
    float4 w0v = *(const float4*)(wq);
    float4 w1v = *(const float4*)(wq + KPAD);
    float4 w2v = *(const float4*)(wq + 2 * KPAD);
    float4 w3v = *(const float4*)(wq + 3 * KPAD);
    float4 w4v = *(const float4*)(wq + 4 * KPAD);
    a0 = fmaf(av.x, w0v.x, a0); a0 = fmaf(av.y, w0v.y, a0);
    a0 = fmaf(av.z, w0v.z, a0); a0 = fmaf(av.w, w0v.w, a0);
    a1 = fmaf(av.x, w1v.x, a1); a1 = fmaf(av.y, w1v.y, a1);
    a1 = fmaf(av.z, w1v.z, a1); a1 = fmaf(av.w, w1v.w, a1);
    a2 = fmaf(av.x, w2v.x, a2); a2 = fmaf(av.y, w2v.y, a2);
    a2 = fmaf(av.z, w2v.z, a2); a2 = fmaf(av.w, w2v.w, a2);
    a3 = fmaf(av.x, w3v.x, a3); a3 = fmaf(av.y, w3v.y, a3);
    a3 = fmaf(av.z, w3v.z, a3); a3 = fmaf(av.w, w3v.w, a3);
    a4 = fmaf(av.x, w4v.x, a4); a4 = fmaf(av.y, w4v.y, a4);
    a4 = fmaf(av.z, w4v.z, a4); a4 = fmaf(av.w, w4v.w, a4);
  }
  float* rp = red + tid * 5;
  rp[0] = a0; rp[1] = a1; rp[2] = a2; rp[3] = a3; rp[4] = a4;
  __syncthreads();
  if (tid < (nc << 6)) {
    int rr = tid / nc;
    int cc = tid - rr * nc;
    float s = 0.f;
#pragma unroll
    for (int q2 = 0; q2 < 8; q2++) s += red[(q2 << 6) * 5 + rr * 5 + cc];
    s += bias[colbase + cc];
    if (RELU) s = fmaxf(s, 0.f);
    int kk = outk_off + colbase + cc;
    __hip_atomic_store(outb + ((size_t)(kk >> 2) << 8) + (rr << 2) + (kk & 3), s,
                       __ATOMIC_RELAXED, __HIP_MEMORY_SCOPE_AGENT);
  }
}

// Persistent decoder: 256 wgs x 512 thr, 3 barriers/step, no atomics.
__global__ __launch_bounds__(512, 1) void decoder_kernel(
    const float* __restrict__ wt1, const float* __restrict__ b1,
    const float* __restrict__ wt2, const float* __restrict__ b2,
    const float* __restrict__ wt3, const float* __restrict__ b3,
    float* __restrict__ comb, float* __restrict__ h1, float* __restrict__ h2,
    unsigned* __restrict__ bar) {
  __shared__ float red[512 * 5];
  const int tid = threadIdx.x;
  const int w = blockIdx.x;
  const int r = tid & 63;
  const int q = __builtin_amdgcn_readfirstlane(tid >> 6);

  // output-column assignments (rem wgs take 5 cols, rest 4)
  const int nc1 = (w < 22) ? 5 : 4;
  const int cb1 = (w < 22) ? w * 5 : 110 + (w - 22) * 4;
  const int nc2 = (w < 11) ? 5 : 4;
  const int cb2 = (w < 11) ? w * 5 : 55 + (w - 11) * 4;
  const int cb3 = w << 2;

  unsigned gen = 0;
  for (int t = 0; t < TT; t++) {
    gen++; gbar(bar, gen << 8);
    const float* actb = comb + (size_t)t * COMB_SLOT;
    dec_phase<NQ1, KP1, true>(actb, wt1, b1, h1, 0, nc1, cb1, r, q, red, tid);
    gen++; gbar(bar, gen << 8);
    dec_phase<NQ2, KP2, true>(h1, wt2, b2, h2, 0, nc2, cb2, r, q, red, tid);
    gen++; gbar(bar, gen << 8);
    dec_phase<NQ3, KP3, false>(h2, wt3, b3, comb + (size_t)(t + 1) * COMB_SLOT, 32,
                               4, cb3, r, q, red, tid);
  }
}

// ---------------------------------------------------------------------------
// comb[t+1][8+Q][b][kk] -> out[b][4Q+kk][t]. grid (256 quads, 4 t-tiles), 256 thr.
__global__ void permute_out2(const float* __restrict__ comb, float* __restrict__ out) {
  __shared__ float tl[64 * 261];  // [r] stride 261, [kk] stride 65, [tt]
  int Q = blockIdx.x;
  int t0 = blockIdx.y << 6;
  int tid = threadIdx.x;
  int r = tid & 63, ts = tid >> 6;  // ts 0..3
#pragma unroll
  for (int i = 0; i < 16; i++) {
    int tt = (i << 2) + ts;
    float4 v = *(const float4*)(comb + ((size_t)(t0 + tt + 1) * 265 + 8 + Q) * 256 + (r << 2));
    float* p = &tl[r * 261];
    p[tt] = v.x; p[65 + tt] = v.y; p[130 + tt] = v.z; p[195 + tt] = v.w;
  }
  __syncthreads();
  int kk = tid & 3, r2 = tid >> 2;
  const float* p = &tl[r2 * 261 + kk * 65];
  float* o = out + ((size_t)r2 * 1024 + (Q << 2) + kk) * 256 + t0;
#pragma unroll
  for (int i = 0; i < 16; i++) {
    int b = i << 2;
    float4 v;
    v.x = p[b]; v.y = p[b + 1]; v.z = p[b + 2]; v.w = p[b + 3];
    *(float4*)(o + b) = v;
  }
}

// ---------------------------------------------------------------------------
extern "C" void kernel_launch(void* const* d_in, const int* in_sizes, int n_in,
                              void* d_out, int out_size, void* d_ws, size_t ws_size,
                              hipStream_t stream) {
  (void)in_sizes; (void)n_in; (void)out_size; (void)ws_size;
  const float* x   = (const float*)d_in[0];
  const float* eW1 = (const float*)d_in[1];
  const float* eb1 = (const float*)d_in[2];
  const float* eW2 = (const float*)d_in[3];
  const float* eb2 = (const float*)d_in[4];
  const float* eW3 = (const float*)d_in[5];
  const float* eb3 = (const float*)d_in[6];
  const float* dW1 = (const float*)d_in[7];
  const float* db1 = (const float*)d_in[8];
  const float* dW2 = (const float*)d_in[9];
  const float* db2 = (const float*)d_in[10];
  const float* dW3 = (const float*)d_in[11];
  const float* db3 = (const float*)d_in[12];

  float* ws    = (float*)d_ws;
  float* xt    = ws + OFF_XT;
  float* wt1p  = ws + OFF_WT1;
  float* wt2p  = ws + OFF_WT2;
  float* wt3p  = ws + OFF_WT3;
  float* h1p   = ws + OFF_H1;
  float* h2p   = ws + OFF_H2;
  float* e1p   = ws + OFF_E1;
  float* e2p   = ws + OFF_E2;
  float* combp = ws + OFF_COMB;
  unsigned* barp = (unsigned*)(ws + OFF_BAR);

  // zero comb slot 0 (t=0 "previous stft" = 0) and barrier
  zero_init<<<dim3(64), dim3(256), 0, stream>>>(combp, (size_t)COMB_SLOT);
  zero_init<<<dim3(1), dim3(64), 0, stream>>>((float*)barp, (size_t)16);

  transpose_x<<<dim3(32, 8, 64), dim3(256), 0, stream>>>(x, xt);

  // encoder (E1 consumes xt; xt region is reused for WT afterwards)
  gemm_enc<1, true,  false><<<dim3(128, 15), dim3(256), 0, stream>>>(xt,  eW1, eb1, e1p, EK1, EN1);
  gemm_enc<0, true,  false><<<dim3(128, 7),  dim3(256), 0, stream>>>(e1p, eW2, eb2, e2p, EN1, EN2);
  gemm_enc<0, false, true ><<<dim3(128, 1),  dim3(256), 0, stream>>>(e2p, eW3, eb3, combp, EN2, EN3);

  // decoder weight transposes (after E1 so xt region is dead)
  transpose_w<<<dim3(33, 34), dim3(256), 0, stream>>>(dW1, wt1p, 1057, DN1, KP1, WROWS1);
  transpose_w<<<dim3(33, 33), dim3(256), 0, stream>>>(dW2, wt2p, 1046, DN2, KP2, WROWS2);
  transpose_w<<<dim3(33, 33), dim3(256), 0, stream>>>(dW3, wt3p, 1035, DN3, KP3, WROWS3);
  init_tail<<<dim3(64), dim3(256), 0, stream>>>(combp);

  // persistent cooperative decoder
  const float *a0 = wt1p, *a1 = db1, *a2 = wt2p, *a3 = db2, *a4 = wt3p, *a5 = db3;
  float *r0 = combp, *r1 = h1p, *r2 = h2p;
  unsigned* r3 = barp;
  void* kargs[] = {&a0, &a1, &a2, &a3, &a4, &a5, &r0, &r1, &r2, &r3};
  hipLaunchCooperativeKernel((void*)decoder_kernel, dim3(256), dim3(512), kargs,
                             0, stream);

  permute_out2<<<dim3(256, 4), dim3(256), 0, stream>>>(combp, (float*)d_out);
}

// Round 4
// 15679.245 us; speedup vs baseline: 2.5165x; 1.4580x over previous
//
#include <hip/hip_runtime.h>
#include <cstdint>
#include <cstddef>

// ---------------------------------------------------------------------------
// StepWiseMLPAutoEncoder (MI355X/gfx950) — round 4: fence-free coherence
//   r3 pathology: per-phase acquire-agent fence invalidated L1+L2 768x ->
//   every weight/act load became an L3-latency miss chain (~26us/phase stall,
//   VALUBusy 5.9%). Now: mutable data (act) is read with agent-scope RELAXED
//   ATOMIC loads (sc0+sc1, bypass L1/L2, read MALL directly) and written with
//   agent-scope relaxed atomic stores -> NO fence anywhere; immutable weights/
//   biases use plain cached loads and stay L1-resident across all 768 phases.
//   Barrier: monotone arrive counter + 8-way distributed release lines.
// ---------------------------------------------------------------------------

#define TT 256
#define BB 64
#define SS 1024

#define EK1 2049
#define EN1 944
#define EN2 416
#define EN3 32

#define DN1 1046
#define DN2 1035
#define DN3 1024

// K paddings (quad-multiples) and padded WT row counts
#define KP1 1060   // 32 ctrl + 1024 prev + 1 t + 3 pad
#define KP2 1048   // 1046 + 2
#define KP3 1036   // 1035 + 1
#define NQ1 265
#define NQ2 262
#define NQ3 259
#define WROWS1 1048
#define WROWS2 1040
#define WROWS3 1028

// ws layout (float offsets)
#define OFF_XT    ((size_t)0)                        // 16,777,216 (xt; reused after E1)
#define OFF_WT1   ((size_t)0)                        //  1048*1060 = 1,110,880
#define OFF_WT2   ((size_t)1110880)                  //  1040*1048 = 1,089,920
#define OFF_WT3   ((size_t)2200800)                  //  1028*1036 = 1,065,008
#define OFF_H1    ((size_t)3265808)                  //  262*256 = 67,072
#define OFF_H2    ((size_t)3332880)                  //  259*256 = 66,304
#define OFF_E1    ((size_t)16777216)                 // 16384*944
#define OFF_E2    ((size_t)(OFF_E1 + 15466496))      // 16384*416
#define OFF_COMB  ((size_t)(OFF_E2 + 6815744))       // 257*265*256 = 17,434,880
#define OFF_BAR   ((size_t)(OFF_COMB + 17434880))    // 512 floats (counter + 8 release lines)
// total = OFF_BAR + 512 = 56,494,848 floats (~226 MB)

#define COMB_SLOT (265 * 256)

// ---------------------------------------------------------------------------
__global__ void zero_init(float* __restrict__ p, size_t n) {
  size_t i = (size_t)blockIdx.x * blockDim.x + threadIdx.x;
  size_t stride = (size_t)gridDim.x * blockDim.x;
  for (; i < n; i += stride) p[i] = 0.f;
}

// x[b][s][t] -> xt[b][t][s]
__global__ void transpose_x(const float* __restrict__ x, float* __restrict__ xt) {
  __shared__ float tile[32][33];
  int b = blockIdx.z;
  int s0 = blockIdx.x << 5;
  int t0 = blockIdx.y << 5;
  int lt = threadIdx.x & 31;
  int ls = threadIdx.x >> 5;
  const float* xp = x + (size_t)b * SS * TT;
#pragma unroll
  for (int i = 0; i < 4; i++) {
    int s = s0 + ls + (i << 3);
    tile[ls + (i << 3)][lt] = xp[(size_t)s * TT + t0 + lt];
  }
  __syncthreads();
  float* xtp = xt + (size_t)b * TT * SS;
#pragma unroll
  for (int i = 0; i < 4; i++) {
    int t = t0 + ls + (i << 3);
    xtp[(size_t)t * SS + s0 + lt] = tile[lt][ls + (i << 3)];
  }
}

// W[k][n] -> WT[c][k], zero-padded to KPAD cols / NCP rows
__global__ void transpose_w(const float* __restrict__ W, float* __restrict__ WT,
                            int K, int N, int KPAD, int NCP) {
  __shared__ float tl[32][33];
  int c0 = blockIdx.x << 5, k0 = blockIdx.y << 5;
  int lx = threadIdx.x & 31, ly = threadIdx.x >> 5;  // 0..7
#pragma unroll
  for (int i = 0; i < 4; i++) {
    int k = k0 + ly + (i << 3);
    int c = c0 + lx;
    tl[ly + (i << 3)][lx] = (k < K && c < N) ? W[(size_t)k * N + c] : 0.f;
  }
  __syncthreads();
#pragma unroll
  for (int i = 0; i < 4; i++) {
    int c = c0 + ly + (i << 3);
    int k = k0 + lx;
    if (c < NCP && k < KPAD) WT[(size_t)c * KPAD + k] = tl[lx][ly + (i << 3)];
  }
}

// comb[t][quad 264][r][0] = t/256, [1..3] = 0
__global__ void init_tail(float* __restrict__ comb) {
  int i = blockIdx.x * blockDim.x + threadIdx.x;  // 0..16383
  int t = i >> 6, r = i & 63;
  float4 v;
  v.x = (float)t * (1.f / 256.f);
  v.y = v.z = v.w = 0.f;
  *(float4*)(comb + ((size_t)t * 265 + 264) * 256 + (r << 2)) = v;
}

// virtual A for encoder layer 1: row m=(b,t), k: [prev(1024) | cur(1024) | t | pad]
__device__ inline float4 e1_fetch(const float* __restrict__ xt, int m, int kg) {
  float4 z; z.x = z.y = z.z = z.w = 0.f;
  int t = m & 255;
  if (kg < 1024) {
    if (t == 0) return z;
    return *(const float4*)(xt + (((size_t)(m - 1)) << 10) + kg);
  } else if (kg < 2048) {
    return *(const float4*)(xt + (((size_t)m) << 10) + (kg - 1024));
  } else if (kg == 2048) {
    z.x = (float)t * (1.0f / 256.0f);
    return z;
  }
  return z;
}

// ---------------------------------------------------------------------------
// Tiled fp32 GEMM: C[M][N] = act(A[M][K] @ B[K][N] + bias). BM=128 BN=64 BK=16.
// SCATTER epilogue writes ctrl into comb prefix: comb[t][n>>2][b][n&3].
template <int AMODE, bool RELU, bool SCATTER>
__global__ __launch_bounds__(256, 2) void gemm_enc(
    const float* __restrict__ A, const float* __restrict__ Bw,
    const float* __restrict__ bias, float* __restrict__ C, int K, int N) {
  __shared__ float As[16][132];
  __shared__ float Bs[16][68];
  const int tid = threadIdx.x;
  const int m0 = blockIdx.x << 7;
  const int n0 = blockIdx.y << 6;
  const int rr = tid >> 4;
  const int cc = tid & 15;
  float acc[8][4];
#pragma unroll
  for (int i = 0; i < 8; i++)
#pragma unroll
    for (int j = 0; j < 4; j++) acc[i][j] = 0.f;

  const int ar = tid >> 2;
  const int akq = (tid & 3) << 2;
  const int bk = tid >> 4;
  const int bn = (tid & 15) << 2;

  for (int k0 = 0; k0 < K; k0 += 16) {
#pragma unroll
    for (int p = 0; p < 2; p++) {
      int m = m0 + ar + (p << 6);
      float4 v;
      if (AMODE == 1) v = e1_fetch(A, m, k0 + akq);
      else            v = *(const float4*)(A + (size_t)m * K + k0 + akq);
      As[akq + 0][ar + (p << 6)] = v.x;
      As[akq + 1][ar + (p << 6)] = v.y;
      As[akq + 2][ar + (p << 6)] = v.z;
      As[akq + 3][ar + (p << 6)] = v.w;
    }
    {
      float4 v; v.x = v.y = v.z = v.w = 0.f;
      if ((k0 + bk) < K && (n0 + bn) < N)
        v = *(const float4*)(Bw + (size_t)(k0 + bk) * N + n0 + bn);
      *(float4*)&Bs[bk][bn] = v;
    }
    __syncthreads();
#pragma unroll
    for (int kk = 0; kk < 16; kk++) {
      float a[8], b4[4];
      *(float4*)&a[0] = *(const float4*)&As[kk][rr << 3];
      *(float4*)&a[4] = *(const float4*)&As[kk][(rr << 3) + 4];
      *(float4*)&b4[0] = *(const float4*)&Bs[kk][cc << 2];
#pragma unroll
      for (int i = 0; i < 8; i++)
#pragma unroll
        for (int j = 0; j < 4; j++) acc[i][j] += a[i] * b4[j];
    }
    __syncthreads();
  }

  if (!SCATTER) {
#pragma unroll
    for (int i = 0; i < 8; i++) {
      int m = m0 + (rr << 3) + i;
      int n = n0 + (cc << 2);
      if (n + 3 < N) {
        float4 o;
        o.x = acc[i][0] + bias[n + 0];
        o.y = acc[i][1] + bias[n + 1];
        o.z = acc[i][2] + bias[n + 2];
        o.w = acc[i][3] + bias[n + 3];
        if (RELU) {
          o.x = fmaxf(o.x, 0.f); o.y = fmaxf(o.y, 0.f);
          o.z = fmaxf(o.z, 0.f); o.w = fmaxf(o.w, 0.f);
        }
        *(float4*)(C + (size_t)m * N + n) = o;
      } else {
#pragma unroll
        for (int j = 0; j < 4; j++) {
          if (n + j < N) {
            float v = acc[i][j] + bias[n + j];
            if (RELU) v = fmaxf(v, 0.f);
            C[(size_t)m * N + n + j] = v;
          }
        }
      }
    }
  } else {
    // ctrl -> comb prefix: m = b*256 + t; comb[t][n>>2][b][n&3]
#pragma unroll
    for (int i = 0; i < 8; i++) {
      int m = m0 + (rr << 3) + i;
      int t = m & 255, b = m >> 8;
#pragma unroll
      for (int j = 0; j < 4; j++) {
        int n = n0 + (cc << 2) + j;
        if (n < EN3)
          C[((size_t)t * 265 + (n >> 2)) * 256 + (b << 2) + (n & 3)] = acc[i][j] + bias[n];
      }
    }
  }
}

// ---------------------------------------------------------------------------
// Global barrier, fence-free. bar[0] = monotone arrive counter; releases at
// bar[32 + i*32] (128B-spaced lines), 32 pollers per line.
// Producer visibility: every wave drains vmcnt(0) at __syncthreads, and all
// mutable-data stores are agent-scope (sc0+sc1, performed at MALL) -> once the
// arrive lands, data IS at the coherence point. Consumers read mutable data
// with agent-scope atomic loads (bypass L1/L2), so no invalidate is needed.
__device__ inline void gbar(unsigned* __restrict__ bar, unsigned gen) {
  __syncthreads();
  if (threadIdx.x == 0) {
    asm volatile("s_waitcnt vmcnt(0)" ::: "memory");
    unsigned old = __hip_atomic_fetch_add(bar, 1u, __ATOMIC_RELAXED, __HIP_MEMORY_SCOPE_AGENT);
    if (old == (gen << 8) - 1u) {
#pragma unroll
      for (int i = 0; i < 8; i++)
        __hip_atomic_store(bar + 32 + i * 32, gen, __ATOMIC_RELAXED, __HIP_MEMORY_SCOPE_AGENT);
    } else {
      unsigned* rel = bar + 32 + (blockIdx.x & 7) * 32;
      while (__hip_atomic_load(rel, __ATOMIC_RELAXED, __HIP_MEMORY_SCOPE_AGENT) < gen)
        __builtin_amdgcn_s_sleep(2);
    }
  }
  __syncthreads();
}

// ---------------------------------------------------------------------------
// One decoder layer phase. actb quad-interleaved [quad][64 r][4], read via
// agent-scope atomic dword loads (MALL-coherent, no fence). wt = WT[c][KPAD]
// plain cached loads (immutable -> L1-resident across phases).
template <int NQ, int KPAD, bool RELU>
__device__ inline void dec_phase(const float* __restrict__ actb,
                                 const float* __restrict__ wt,
                                 const float* __restrict__ bias,
                                 float* __restrict__ outb, int outk_off,
                                 int nc, int colbase, int r, int q,
                                 float* __restrict__ red, int tid) {
  float a0 = 0.f, a1 = 0.f, a2 = 0.f, a3 = 0.f, a4 = 0.f;
  const float* w0 = wt + (size_t)colbase * KPAD;
#pragma unroll 4
  for (int j = q; j < NQ; j += 8) {
    const float* ap = actb + (j << 8) + (r << 2);
    float ax = __hip_atomic_load(ap + 0, __ATOMIC_RELAXED, __HIP_MEMORY_SCOPE_AGENT);
    float ay = __hip_atomic_load(ap + 1, __ATOMIC_RELAXED, __HIP_MEMORY_SCOPE_AGENT);
    float az = __hip_atomic_load(ap + 2, __ATOMIC_RELAXED, __HIP_MEMORY_SCOPE_AGENT);
    float aw = __hip_atomic_load(ap + 3, __ATOMIC_RELAXED, __HIP_MEMORY_SCOPE_AGENT);
    const float* wq = w0 + (j << 2);
    float4 w0v = *(const float4*)(wq);
    float4 w1v = *(const float4*)(wq + KPAD);
    float4 w2v = *(const float4*)(wq + 2 * KPAD);
    float4 w3v = *(const float4*)(wq + 3 * KPAD);
    float4 w4v = *(const float4*)(wq + 4 * KPAD);
    a0 = fmaf(ax, w0v.x, a0); a0 = fmaf(ay, w0v.y, a0);
    a0 = fmaf(az, w0v.z, a0); a0 = fmaf(aw, w0v.w, a0);
    a1 = fmaf(ax, w1v.x, a1); a1 = fmaf(ay, w1v.y, a1);
    a1 = fmaf(az, w1v.z, a1); a1 = fmaf(aw, w1v.w, a1);
    a2 = fmaf(ax, w2v.x, a2); a2 = fmaf(ay, w2v.y, a2);
    a2 = fmaf(az, w2v.z, a2); a2 = fmaf(aw, w2v.w, a2);
    a3 = fmaf(ax, w3v.x, a3); a3 = fmaf(ay, w3v.y, a3);
    a3 = fmaf(az, w3v.z, a3); a3 = fmaf(aw, w3v.w, a3);
    a4 = fmaf(ax, w4v.x, a4); a4 = fmaf(ay, w4v.y, a4);
    a4 = fmaf(az, w4v.z, a4); a4 = fmaf(aw, w4v.w, a4);
  }
  float* rp = red + tid * 5;
  rp[0] = a0; rp[1] = a1; rp[2] = a2; rp[3] = a3; rp[4] = a4;
  __syncthreads();
  if (tid < (nc << 6)) {
    int rr = tid / nc;
    int cc = tid - rr * nc;
    float s = 0.f;
#pragma unroll
    for (int q2 = 0; q2 < 8; q2++) s += red[(q2 << 6) * 5 + rr * 5 + cc];
    s += bias[colbase + cc];
    if (RELU) s = fmaxf(s, 0.f);
    int kk = outk_off + colbase + cc;
    __hip_atomic_store(outb + ((size_t)(kk >> 2) << 8) + (rr << 2) + (kk & 3), s,
                       __ATOMIC_RELAXED, __HIP_MEMORY_SCOPE_AGENT);
  }
}

// Persistent decoder: 256 wgs x 512 thr, 3 barriers/step, no atomics, no fences.
__global__ __launch_bounds__(512, 1) void decoder_kernel(
    const float* __restrict__ wt1, const float* __restrict__ b1,
    const float* __restrict__ wt2, const float* __restrict__ b2,
    const float* __restrict__ wt3, const float* __restrict__ b3,
    float* __restrict__ comb, float* __restrict__ h1, float* __restrict__ h2,
    unsigned* __restrict__ bar) {
  __shared__ float red[512 * 5];
  const int tid = threadIdx.x;
  const int w = blockIdx.x;
  const int r = tid & 63;
  const int q = __builtin_amdgcn_readfirstlane(tid >> 6);

  // output-column assignments (rem wgs take 5 cols, rest 4)
  const int nc1 = (w < 22) ? 5 : 4;
  const int cb1 = (w < 22) ? w * 5 : 110 + (w - 22) * 4;
  const int nc2 = (w < 11) ? 5 : 4;
  const int cb2 = (w < 11) ? w * 5 : 55 + (w - 11) * 4;
  const int cb3 = w << 2;

  unsigned gen = 0;
  for (int t = 0; t < TT; t++) {
    gen++; gbar(bar, gen);
    const float* actb = comb + (size_t)t * COMB_SLOT;
    dec_phase<NQ1, KP1, true>(actb, wt1, b1, h1, 0, nc1, cb1, r, q, red, tid);
    gen++; gbar(bar, gen);
    dec_phase<NQ2, KP2, true>(h1, wt2, b2, h2, 0, nc2, cb2, r, q, red, tid);
    gen++; gbar(bar, gen);
    dec_phase<NQ3, KP3, false>(h2, wt3, b3, comb + (size_t)(t + 1) * COMB_SLOT, 32,
                               4, cb3, r, q, red, tid);
  }
}

// ---------------------------------------------------------------------------
// comb[t+1][8+Q][b][kk] -> out[b][4Q+kk][t]. grid (256 quads, 4 t-tiles), 256 thr.
__global__ void permute_out2(const float* __restrict__ comb, float* __restrict__ out) {
  __shared__ float tl[64 * 261];  // [r] stride 261, [kk] stride 65, [tt]
  int Q = blockIdx.x;
  int t0 = blockIdx.y << 6;
  int tid = threadIdx.x;
  int r = tid & 63, ts = tid >> 6;  // ts 0..3
#pragma unroll
  for (int i = 0; i < 16; i++) {
    int tt = (i << 2) + ts;
    float4 v = *(const float4*)(comb + ((size_t)(t0 + tt + 1) * 265 + 8 + Q) * 256 + (r << 2));
    float* p = &tl[r * 261];
    p[tt] = v.x; p[65 + tt] = v.y; p[130 + tt] = v.z; p[195 + tt] = v.w;
  }
  __syncthreads();
  int kk = tid & 3, r2 = tid >> 2;
  const float* p = &tl[r2 * 261 + kk * 65];
  float* o = out + ((size_t)r2 * 1024 + (Q << 2) + kk) * 256 + t0;
#pragma unroll
  for (int i = 0; i < 16; i++) {
    int b = i << 2;
    float4 v;
    v.x = p[b]; v.y = p[b + 1]; v.z = p[b + 2]; v.w = p[b + 3];
    *(float4*)(o + b) = v;
  }
}

// ---------------------------------------------------------------------------
extern "C" void kernel_launch(void* const* d_in, const int* in_sizes, int n_in,
                              void* d_out, int out_size, void* d_ws, size_t ws_size,
                              hipStream_t stream) {
  (void)in_sizes; (void)n_in; (void)out_size; (void)ws_size;
  const float* x   = (const float*)d_in[0];
  const float* eW1 = (const float*)d_in[1];
  const float* eb1 = (const float*)d_in[2];
  const float* eW2 = (const float*)d_in[3];
  const float* eb2 = (const float*)d_in[4];
  const float* eW3 = (const float*)d_in[5];
  const float* eb3 = (const float*)d_in[6];
  const float* dW1 = (const float*)d_in[7];
  const float* db1 = (const float*)d_in[8];
  const float* dW2 = (const float*)d_in[9];
  const float* db2 = (const float*)d_in[10];
  const float* dW3 = (const float*)d_in[11];
  const float* db3 = (const float*)d_in[12];

  float* ws    = (float*)d_ws;
  float* xt    = ws + OFF_XT;
  float* wt1p  = ws + OFF_WT1;
  float* wt2p  = ws + OFF_WT2;
  float* wt3p  = ws + OFF_WT3;
  float* h1p   = ws + OFF_H1;
  float* h2p   = ws + OFF_H2;
  float* e1p   = ws + OFF_E1;
  float* e2p   = ws + OFF_E2;
  float* combp = ws + OFF_COMB;
  unsigned* barp = (unsigned*)(ws + OFF_BAR);

  // zero comb slot 0 (t=0 "previous stft" = 0) and barrier region
  zero_init<<<dim3(64), dim3(256), 0, stream>>>(combp, (size_t)COMB_SLOT);
  zero_init<<<dim3(1), dim3(256), 0, stream>>>((float*)barp, (size_t)512);

  transpose_x<<<dim3(32, 8, 64), dim3(256), 0, stream>>>(x, xt);

  // encoder (E1 consumes xt; xt region is reused for WT afterwards)
  gemm_enc<1, true,  false><<<dim3(128, 15), dim3(256), 0, stream>>>(xt,  eW1, eb1, e1p, EK1, EN1);
  gemm_enc<0, true,  false><<<dim3(128, 7),  dim3(256), 0, stream>>>(e1p, eW2, eb2, e2p, EN1, EN2);
  gemm_enc<0, false, true ><<<dim3(128, 1),  dim3(256), 0, stream>>>(e2p, eW3, eb3, combp, EN2, EN3);

  // decoder weight transposes (after E1 so xt region is dead)
  transpose_w<<<dim3(33, 34), dim3(256), 0, stream>>>(dW1, wt1p, 1057, DN1, KP1, WROWS1);
  transpose_w<<<dim3(33, 33), dim3(256), 0, stream>>>(dW2, wt2p, 1046, DN2, KP2, WROWS2);
  transpose_w<<<dim3(33, 33), dim3(256), 0, stream>>>(dW3, wt3p, 1035, DN3, KP3, WROWS3);
  init_tail<<<dim3(64), dim3(256), 0, stream>>>(combp);

  // persistent cooperative decoder
  const float *a0 = wt1p, *a1 = db1, *a2 = wt2p, *a3 = db2, *a4 = wt3p, *a5 = db3;
  float *r0 = combp, *r1 = h1p, *r2 = h2p;
  unsigned* r3 = barp;
  void* kargs[] = {&a0, &a1, &a2, &a3, &a4, &a5, &r0, &r1, &r2, &r3};
  hipLaunchCooperativeKernel((void*)decoder_kernel, dim3(256), dim3(512), kargs,
                             0, stream);

  permute_out2<<<dim3(256, 4), dim3(256), 0, stream>>>(combp, (float*)d_out);
}